// Round 17
// baseline (522.403 us; speedup 1.0000x reference)
//
#include <hip/hip_runtime.h>
#include <hip/hip_bf16.h>
#include <math.h>

#define KP 6
#define BATCH 256
#define DIM 768
#define NMEM 32768
#define NXBLK (NMEM / 128)   // col-blocks per row = 256
#define NROWS (KP * BATCH)   // 1536

typedef __attribute__((ext_vector_type(8))) short bf16x8;
typedef __attribute__((ext_vector_type(4))) float f32x4;

__device__ inline uint bf16rne(float x) {
  uint u = __builtin_bit_cast(uint, x);
  return (u + 0x7fffu + ((u >> 16) & 1u)) >> 16;
}
__device__ inline uint pk2(float lo, float hi) {
  return bf16rne(lo) | (bf16rne(hi) << 16);
}
// packed cvt via casts (clang emits v_cvt_pk_bf16_f32 pairs; m240: don't hand-asm)
__device__ inline uint cvt2(float lo, float hi) {
  return (uint)__builtin_bit_cast(ushort, __float2bfloat16(lo)) |
         ((uint)__builtin_bit_cast(ushort, __float2bfloat16(hi)) << 16);
}
// bf16 tile swizzle (64B rows): flip 16B-unit bits 4-5 with row bits 1-2.
__device__ inline int swz(int b) { return b ^ (((b >> 7) & 3) << 4); }

// ---------------- prep (F only): fp64 inv-norms + bf16 copy ----------------

__global__ __launch_bounds__(256) void prep_kernel(const float* __restrict__ X,
                                                   ushort* __restrict__ Xb,
                                                   double* __restrict__ invX,
                                                   int nrows) {
  int wid = threadIdx.x >> 6, lane = threadIdx.x & 63;
  int row = blockIdx.x * 4 + wid;
  if (row >= nrows) return;
  const float* x = X + (size_t)row * DIM;
  ushort* xb = Xb + (size_t)row * DIM;
  double s = 0.0;
#pragma unroll
  for (int i = 0; i < 3; ++i) {
    int d = i * 256 + lane * 4;
    float4 v = *reinterpret_cast<const float4*>(x + d);
    s += (double)v.x * v.x + (double)v.y * v.y;
    s += (double)v.z * v.z + (double)v.w * v.w;
    uint2 p; p.x = pk2(v.x, v.y); p.y = pk2(v.z, v.w);
    *reinterpret_cast<uint2*>(xb + d) = p;
  }
  for (int off = 32; off > 0; off >>= 1) s += __shfl_down(s, off);
  if (lane == 0) invX[row] = 1.0 / fmax(sqrt(s), 1e-12);
}

// ------ fused GEMM (r10 lineage, r17 change: A fragments loaded DIRECTLY ----
// ------ from global bf16 Fb (2.4 MB, LLC-resident) — no A-LDS, no A-DMA, ----
// ------ ONE barrier/step, no manual vmcnt (compiler tracks reg loads).  ----

#define GBM 128
#define GBN 128
#define GBK 32
#define NKT (DIM / GBK)  // 24
#define CHS 132          // epilogue chunk row stride in floats

__global__ __launch_bounds__(256, 4) void gemm_kernel(
    const float* __restrict__ M, const ushort* __restrict__ Fb,
    const double* __restrict__ invF, double* __restrict__ invMg,
    float* __restrict__ sim, float* __restrict__ soft, float2* __restrict__ P) {
  // bijective XCD swizzle: 3072 wg = 8 xcd x 384; m-tile pair adjacent per XCD
  int lin = blockIdx.x;
  int wg = (lin & 7) * 384 + (lin >> 3);
  int k = wg >> 9;
  int bm0 = (wg & 1) * GBM;
  int ntile = (wg >> 1) & 255;
  int bn0 = ntile * GBN;
  const ushort* Fk = Fb + (size_t)k * BATCH * DIM;
  const float* Mk = M + (size_t)k * NMEM * DIM;

  __shared__ __align__(16) char smem[33280];
  ushort* B0 = (ushort*)(smem + 16384);       // 8 KB bf16 each (r10 addresses)
  ushort* B1 = (ushort*)(smem + 24576);
  float* invml = (float*)(smem + 32768);      // 512 B

  int tid = threadIdx.x;
  int lane = tid & 63, wave = tid >> 6;
  int wr = (wave >> 1) * 64, wc = (wave & 1) * 64;
  int l15 = lane & 15, lch = lane >> 4;
  int rgrp = lch << 2;

  // ---- A fragments direct from global (K-invariant bases, +t*32 imm) ----
  const ushort* gA[4];
#pragma unroll
  for (int i = 0; i < 4; ++i)
    gA[i] = Fk + (size_t)(bm0 + wr + i * 16 + l15) * DIM + lch * 8;

  // ---- B reg staging: thread t -> row tid>>1, half (tid&1)*16 floats ----
  int rB = tid >> 1, hB = tid & 1;
  const float4* gBp =
      reinterpret_cast<const float4*>(Mk + (size_t)(bn0 + rB) * DIM + hB * 16);
  int wb0 = swz(rB * 64 + hB * 32);       // both-sides swizzled ds_write addrs
  int wb1 = swz(rB * 64 + hB * 32 + 16);  // (8 lanes/bank-quad: conflict-free)

  // ---- B fragment read offsets (K-invariant, swizzled) ----
  int boff[4];
#pragma unroll
  for (int i = 0; i < 4; ++i)
    boff[i] = swz((wc + i * 16 + l15) * 64 + lch * 16);

  f32x4 acc[4][4];
#pragma unroll
  for (int i = 0; i < 4; ++i)
#pragma unroll
    for (int j = 0; j < 4; ++j) acc[i][j] = (f32x4){0.f, 0.f, 0.f, 0.f};
  float4 bq0, bq1, bq2, bq3;  // single B reg set (static names, rule #20)
  float sq = 0.f;             // per-thread sumsq of its B half-row

#define LOADB(t)                 \
  do {                           \
    bq0 = gBp[(t) * 8 + 0];      \
    bq1 = gBp[(t) * 8 + 1];      \
    bq2 = gBp[(t) * 8 + 2];      \
    bq3 = gBp[(t) * 8 + 3];      \
  } while (0)

#define WRITEB(Bb)                                                          \
  do {                                                                     \
    sq = fmaf(bq0.x, bq0.x, sq); sq = fmaf(bq0.y, bq0.y, sq);              \
    sq = fmaf(bq0.z, bq0.z, sq); sq = fmaf(bq0.w, bq0.w, sq);              \
    sq = fmaf(bq1.x, bq1.x, sq); sq = fmaf(bq1.y, bq1.y, sq);              \
    sq = fmaf(bq1.z, bq1.z, sq); sq = fmaf(bq1.w, bq1.w, sq);              \
    sq = fmaf(bq2.x, bq2.x, sq); sq = fmaf(bq2.y, bq2.y, sq);              \
    sq = fmaf(bq2.z, bq2.z, sq); sq = fmaf(bq2.w, bq2.w, sq);              \
    sq = fmaf(bq3.x, bq3.x, sq); sq = fmaf(bq3.y, bq3.y, sq);              \
    sq = fmaf(bq3.z, bq3.z, sq); sq = fmaf(bq3.w, bq3.w, sq);              \
    uint4 w0, w1;                                                          \
    w0.x = cvt2(bq0.x, bq0.y); w0.y = cvt2(bq0.z, bq0.w);                  \
    w0.z = cvt2(bq1.x, bq1.y); w0.w = cvt2(bq1.z, bq1.w);                  \
    w1.x = cvt2(bq2.x, bq2.y); w1.y = cvt2(bq2.z, bq2.w);                  \
    w1.z = cvt2(bq3.x, bq3.y); w1.w = cvt2(bq3.z, bq3.w);                  \
    *reinterpret_cast<uint4*>((char*)(Bb) + wb0) = w0;                     \
    *reinterpret_cast<uint4*>((char*)(Bb) + wb1) = w1;                     \
  } while (0)

#define COMPUTE(t, Bb)                                                         \
  do {                                                                         \
    bf16x8 af[4], bfr[4];                                                      \
    _Pragma("unroll") for (int i = 0; i < 4; ++i)                              \
        af[i] = *reinterpret_cast<const bf16x8*>(gA[i] + (t) * 32);            \
    _Pragma("unroll") for (int i = 0; i < 4; ++i)                              \
        bfr[i] = *reinterpret_cast<const bf16x8*>((const char*)(Bb) + boff[i]);\
    _Pragma("unroll") for (int i = 0; i < 4; ++i)                              \
        _Pragma("unroll") for (int j = 0; j < 4; ++j) acc[i][j] =              \
            __builtin_amdgcn_mfma_f32_16x16x32_bf16(af[i], bfr[j], acc[i][j],  \
                                                    0, 0, 0);                  \
  } while (0)

#define LGKM0 asm volatile("s_waitcnt lgkmcnt(0)" ::: "memory")
#define BARR __builtin_amdgcn_s_barrier()
#define SB0 __builtin_amdgcn_sched_barrier(0)

  // prologue (compiler inserts the bq waits)
  LOADB(0);
  WRITEB(B0);
  LOADB(1);
  LGKM0; BARR; SB0;

  // one barrier per step: WRITEB targets B[(t+1)&1], last READ at iter t-1
  // behind the end-of-iter barrier -> safe; the barrier also guarantees all
  // waves' COMPUTE(t) ds_reads completed (MFMA issue implies lgkm-waited)
  // before any wave's iter-t+1 WRITEB overwrites B[t&1].
#pragma unroll
  for (int t = 0; t < NKT; ++t) {
    const ushort* Bb = (t & 1) ? B1 : B0;
    COMPUTE(t, Bb);
    if (t < NKT - 1) {
      ushort* Bw = (t & 1) ? B0 : B1;   // (t+1)&1
      WRITEB(Bw);
      if (t < NKT - 2) LOADB(t + 2);
      LGKM0; BARR; SB0;
    }
  }

  // ---- invM from reg-accumulated sumsq (each element counted once) ----
  __syncthreads();  // loop fully done; drains outstanding counters
  {
    float s2 = sq + __shfl_xor(sq, 1);  // pair (2r, 2r+1) -> full row r
    if (hB == 0) {
      double inv = 1.0 / fmax(sqrt((double)s2), 1e-12);
      invml[rB] = (float)inv;
      if (bm0 == 0) invMg[(size_t)k * NMEM + bn0 + rB] = inv;
    }
  }
  __syncthreads();

  // ---------- epilogue (identical to r10) ----------
  size_t kb = (size_t)k * BATCH;
  float fi[4][4];
#pragma unroll
  for (int i = 0; i < 4; ++i)
#pragma unroll
    for (int r = 0; r < 4; ++r)
      fi[i][r] = (float)invF[kb + bm0 + wr + i * 16 + rgrp + r];
  float im[4];
#pragma unroll
  for (int j = 0; j < 4; ++j) im[j] = invml[wc + j * 16 + l15];

  // soft zero-block (coalesced float4); top-5 scatter happens in merge
  {
    const f32x4 z = (f32x4){0.f, 0.f, 0.f, 0.f};
#pragma unroll
    for (int p = 0; p < 16; ++p) {
      int u = p * 256 + tid;
      int row = u >> 5, unit = u & 31;
      *reinterpret_cast<f32x4*>(soft + (kb + bm0 + row) * NMEM + bn0 + unit * 4) = z;
    }
  }

  // 4 quarters of 32 rows: acc -> LDS chunk -> coalesced sim store + top-4 scan
  // qt loop fully unrolled (rule #20: runtime-indexed acc -> scratch disaster)
  float* chunk = (float*)smem;                  // 16896 B
  float2* lists = (float2*)(smem + 24576);      // 8192 B
#pragma unroll
  for (int qt = 0; qt < 4; ++qt) {
    __syncthreads();
    if (wr == (qt >> 1) * 64) {
      const int ibase = (qt & 1) * 2;
#pragma unroll
      for (int ii = 0; ii < 2; ++ii) {
        const int i = ibase + ii;
        int rc0 = ii * 16 + rgrp;
#pragma unroll
        for (int j = 0; j < 4; ++j)
#pragma unroll
          for (int r = 0; r < 4; ++r)
            chunk[(rc0 + r) * CHS + wc + j * 16 + l15] =
                acc[i][j][r] * fi[i][r] * im[j];
      }
    }
    __syncthreads();
    int grow = bm0 + qt * 32;
#pragma unroll
    for (int uu = 0; uu < 4; ++uu) {
      int u = uu * 256 + tid;
      int rc = u >> 5, cu = u & 31;
      f32x4 v = *reinterpret_cast<const f32x4*>(chunk + rc * CHS + cu * 4);
      *reinterpret_cast<f32x4*>(sim + (kb + grow + rc) * NMEM + bn0 + cu * 4) = v;
    }
    int rc = tid >> 3, q8 = tid & 7;
    float v4[4] = {-INFINITY, -INFINITY, -INFINITY, -INFINITY};
    int i4[4] = {0, 0, 0, 0};
#pragma unroll
    for (int j = 0; j < 16; ++j) {
      int cc = q8 + 8 * j;
      float v = chunk[rc * CHS + cc];
      if (v > v4[3]) {
        v4[3] = v; i4[3] = cc;
        if (v4[3] > v4[2]) { float t = v4[3]; v4[3] = v4[2]; v4[2] = t; int s = i4[3]; i4[3] = i4[2]; i4[2] = s; }
        if (v4[2] > v4[1]) { float t = v4[2]; v4[2] = v4[1]; v4[1] = t; int s = i4[2]; i4[2] = i4[1]; i4[1] = s; }
        if (v4[1] > v4[0]) { float t = v4[1]; v4[1] = v4[0]; v4[0] = t; int s = i4[1]; i4[1] = i4[0]; i4[0] = s; }
      }
    }
#pragma unroll
    for (int s = 0; s < 4; ++s)
      lists[(rc * 8 + q8) * 4 + s] = make_float2(v4[s], __builtin_bit_cast(float, i4[s]));
    __syncthreads();
    if (q8 == 0) {
      float mv[4] = {-INFINITY, -INFINITY, -INFINITY, -INFINITY};
      int mi[4] = {0, 0, 0, 0};
#pragma unroll
      for (int e = 0; e < 32; ++e) {
        float2 pe = lists[rc * 32 + e];
        float v = pe.x; int ix = __builtin_bit_cast(int, pe.y);
        if (v > mv[3]) {
          mv[3] = v; mi[3] = ix;
          if (mv[3] > mv[2]) { float t = mv[3]; mv[3] = mv[2]; mv[2] = t; int s = mi[3]; mi[3] = mi[2]; mi[2] = s; }
          if (mv[2] > mv[1]) { float t = mv[2]; mv[2] = mv[1]; mv[1] = t; int s = mi[2]; mi[2] = mi[1]; mi[1] = s; }
          if (mv[1] > mv[0]) { float t = mv[1]; mv[1] = mv[0]; mv[0] = t; int s = mi[1]; mi[1] = mi[0]; mi[0] = s; }
        }
      }
      float2* Prow = P + ((size_t)(kb + grow + rc) * NXBLK + ntile) * 4;
#pragma unroll
      for (int s = 0; s < 4; ++s)
        Prow[s] = make_float2(mv[s], __builtin_bit_cast(float, mi[s] + bn0));
    }
  }
#undef LOADB
#undef WRITEB
#undef COMPUTE
#undef LGKM0
#undef BARR
#undef SB0
}

// ---------------- merge partials + fp64 refine + softmax + entropy ----------

__global__ __launch_bounds__(256) void merge_kernel(
    const float* __restrict__ F, const float* __restrict__ M,
    const double* __restrict__ invF, const double* __restrict__ invM,
    const float2* __restrict__ P, float* __restrict__ soft,
    float* __restrict__ ent) {
  int kb = blockIdx.x;  // 0..1535
  int k = kb / BATCH;
  int tid = threadIdx.x;
  float* orow = soft + (size_t)kb * NMEM;

  __shared__ float sval[1024];
  __shared__ int   sidx[1024];
  const float2* Prow = P + (size_t)kb * NXBLK * 4;
#pragma unroll
  for (int j = 0; j < 4; ++j) {
    float2 e = Prow[tid * 4 + j];
    sval[tid * 4 + j] = e.x;
    sidx[tid * 4 + j] = __builtin_bit_cast(int, e.y);
  }
  __syncthreads();

  __shared__ float rv[256]; __shared__ int rp[256];
  __shared__ float cand_v[8]; __shared__ int cand_i[8];
  for (int r = 0; r < 8; ++r) {
    float best = -INFINITY; int bpos = tid * 4;
#pragma unroll
    for (int j = 0; j < 4; ++j) {
      float v = sval[tid * 4 + j];
      if (v > best) { best = v; bpos = tid * 4 + j; }
    }
    rv[tid] = best; rp[tid] = bpos;
    __syncthreads();
    for (int st = 128; st > 0; st >>= 1) {
      if (tid < st && rv[tid + st] > rv[tid]) { rv[tid] = rv[tid + st]; rp[tid] = rp[tid + st]; }
      __syncthreads();
    }
    if (tid == 0) {
      cand_v[r] = rv[0]; cand_i[r] = sidx[rp[0]];
      sval[rp[0]] = -INFINITY;
    }
    __syncthreads();
  }

  // fp64 refinement of the 8 candidates (exact re-ranking at the 5/6 boundary)
  __shared__ double dred[256];
  __shared__ double cval[8];
  const float* fr = F + (size_t)kb * DIM;
  double invf = invF[kb];
  for (int c = 0; c < 8; ++c) {
    const float* mr = M + ((size_t)k * NMEM + cand_i[c]) * DIM;
    double s = 0.0;
    for (int d = tid; d < DIM; d += 256) s += (double)fr[d] * (double)mr[d];
    dred[tid] = s; __syncthreads();
    for (int st = 128; st > 0; st >>= 1) {
      if (tid < st) dred[tid] += dred[tid + st];
      __syncthreads();
    }
    if (tid == 0) cval[c] = dred[0] * invf * invM[(size_t)k * NMEM + cand_i[c]];
    __syncthreads();
  }

  if (tid == 0) {
    int ord[8];
    for (int i = 0; i < 8; ++i) ord[i] = i;
    for (int i = 0; i < 5; ++i) {
      int best = i;
      for (int j = i + 1; j < 8; ++j) {
        float fa = (float)cval[ord[j]], fb = (float)cval[ord[best]];
        bool better = (fa != fb) ? (fa > fb) : (cand_i[ord[j]] < cand_i[ord[best]]);
        if (better) best = j;
      }
      int t = ord[i]; ord[i] = ord[best]; ord[best] = t;
    }
    float v5[5]; int i5[5];
    float vmax = -INFINITY;
    for (int i = 0; i < 5; ++i) {
      v5[i] = cand_v[ord[i]]; i5[i] = cand_i[ord[i]];
      vmax = fmaxf(vmax, v5[i]);
    }
    float e[5], Z = 0.f;
    float xm = vmax / 3.0f;
    for (int i = 0; i < 5; ++i) { e[i] = expf(v5[i] / 3.0f - xm); Z += e[i]; }
    float ent_s = 0.f;
    for (int i = 0; i < 5; ++i) {
      float p = e[i] / Z;
      orow[i5[i]] = p;
      ent_s += p * logf(p);
    }
    float tiny = 1e-8f * logf(1e-8f);
    ent[kb] = -(ent_s + (float)(NMEM - 5) * tiny);
  }
}

// ---------------- entropy weights ----------------

__global__ __launch_bounds__(256) void w_kernel(const float* __restrict__ ent,
                                                float* __restrict__ wout) {
  int k = blockIdx.x; int tid = threadIdx.x;
  float e = ent[k * BATCH + tid];
  float wv = expf(-e);
  __shared__ float red[256];
  red[tid] = wv; __syncthreads();
  for (int st = 128; st > 0; st >>= 1) {
    if (tid < st) red[tid] += red[tid + st];
    __syncthreads();
  }
  float mean = red[0] / (float)BATCH;
  wout[k * BATCH + tid] = wv / (mean + 1e-8f);
}

// ---------------- launch ----------------

extern "C" void kernel_launch(void* const* d_in, const int* in_sizes, int n_in,
                              void* d_out, int out_size, void* d_ws, size_t ws_size,
                              hipStream_t stream) {
  (void)in_sizes; (void)n_in; (void)out_size; (void)ws_size;
  const float* F = (const float*)d_in[0];   // [KP, BATCH, DIM] fp32
  const float* M = (const float*)d_in[1];   // [KP, NMEM, DIM] fp32
  float* out = (float*)d_out;
  size_t simsz = (size_t)KP * BATCH * NMEM;
  float* soft = out;
  float* sim = out + simsz;
  float* wout = out + 2 * simsz;

  // workspace: Fb bf16 (2.4 MB) + invM f64 + invF f64 + ent + P (~16 MB)
  ushort* Fb = (ushort*)d_ws;                               // KP*BATCH*DIM bf16
  double* invM = (double*)(Fb + (size_t)KP * BATCH * DIM);  // KP*NMEM f64
  double* invF = invM + (size_t)KP * NMEM;                  // KP*BATCH f64
  float* ent = (float*)(invF + KP * BATCH);                 // KP*BATCH f32
  float2* P = (float2*)(ent + NROWS);                       // NROWS*NXBLK*4 float2

  prep_kernel<<<KP * BATCH / 4, 256, 0, stream>>>(F, Fb, invF, KP * BATCH);
  gemm_kernel<<<(BATCH / GBM) * (NMEM / GBN) * KP, 256, 0, stream>>>(M, Fb, invF, invM, sim, soft, P);
  merge_kernel<<<NROWS, 256, 0, stream>>>(F, M, invF, invM, P, soft, ent);
  w_kernel<<<KP, 256, 0, stream>>>(ent, wout);
}

// Round 18
// 408.939 us; speedup vs baseline: 1.2775x; 1.2775x over previous
//
#include <hip/hip_runtime.h>
#include <hip/hip_bf16.h>
#include <math.h>

#define KP 6
#define BATCH 256
#define DIM 768
#define NMEM 32768
#define NXBLK (NMEM / 64)    // 64-col tiles per row = 512
#define NROWS (KP * BATCH)   // 1536

typedef __attribute__((ext_vector_type(8))) short bf16x8;
typedef __attribute__((ext_vector_type(4))) float f32x4;

__device__ inline uint bf16rne(float x) {
  uint u = __builtin_bit_cast(uint, x);
  return (u + 0x7fffu + ((u >> 16) & 1u)) >> 16;
}
__device__ inline uint pk2(float lo, float hi) {
  return bf16rne(lo) | (bf16rne(hi) << 16);
}
// packed cvt via casts (clang emits v_cvt_pk_bf16_f32 pairs; m240: don't hand-asm)
__device__ inline uint cvt2(float lo, float hi) {
  return (uint)__builtin_bit_cast(ushort, __float2bfloat16(lo)) |
         ((uint)__builtin_bit_cast(ushort, __float2bfloat16(hi)) << 16);
}
// bf16 tile swizzle (64B rows): flip 16B-unit bits 4-5 with row bits 1-2.
__device__ inline int swz(int b) { return b ^ (((b >> 7) & 3) << 4); }

__device__ inline void gld_lds16(const void* g, void* l) {
  __builtin_amdgcn_global_load_lds(
      (const __attribute__((address_space(1))) void*)g,
      (__attribute__((address_space(3))) void*)l, 16, 0, 0);
}

// ---------------- prep (F only): fp64 inv-norms + bf16 copy ----------------

__global__ __launch_bounds__(256) void prep_kernel(const float* __restrict__ X,
                                                   ushort* __restrict__ Xb,
                                                   double* __restrict__ invX,
                                                   int nrows) {
  int wid = threadIdx.x >> 6, lane = threadIdx.x & 63;
  int row = blockIdx.x * 4 + wid;
  if (row >= nrows) return;
  const float* x = X + (size_t)row * DIM;
  ushort* xb = Xb + (size_t)row * DIM;
  double s = 0.0;
#pragma unroll
  for (int i = 0; i < 3; ++i) {
    int d = i * 256 + lane * 4;
    float4 v = *reinterpret_cast<const float4*>(x + d);
    s += (double)v.x * v.x + (double)v.y * v.y;
    s += (double)v.z * v.z + (double)v.w * v.w;
    uint2 p; p.x = pk2(v.x, v.y); p.y = pk2(v.z, v.w);
    *reinterpret_cast<uint2*>(xb + d) = p;
  }
  for (int off = 32; off > 0; off >>= 1) s += __shfl_down(s, off);
  if (lane == 0) invX[row] = 1.0 / fmax(sqrt(s), 1e-12);
}

// ------ fused GEMM (r10 loop EXACT; r18: 128x64 tile, acc[4][2]=32 AGPR so
// ------ total regs fit the <=128 tier WITHOUT spill -> 16 waves/CU (2x TLP).
// ------ r11-r17 lesson: schedule is fine, occupancy was VGPR-capped at 8. ----

#define GBM 128
#define GBN 64
#define GBK 32
#define NKT (DIM / GBK)  // 24
#define CHS 68           // epilogue chunk row stride in floats

__global__ __launch_bounds__(256, 4) void gemm_kernel(
    const float* __restrict__ M, const ushort* __restrict__ Fb,
    const double* __restrict__ invF, double* __restrict__ invMg,
    float* __restrict__ sim, float* __restrict__ soft, float2* __restrict__ P) {
  // bijective XCD swizzle: 6144 wg = 8 xcd x 768; m-tile pair adjacent per XCD
  int lin = blockIdx.x;
  int wg = (lin & 7) * 768 + (lin >> 3);
  int k = wg >> 10;
  int rem = wg & 1023;
  int ntile = rem >> 1;        // 0..511
  int bm0 = (rem & 1) * GBM;
  int bn0 = ntile * GBN;
  const ushort* Fk = Fb + (size_t)k * BATCH * DIM;
  const float* Mk = M + (size_t)k * NMEM * DIM;

  __shared__ __align__(16) char smem[24832];
  ushort* A0 = (ushort*)smem;                 // 8 KB bf16 each (128 rows x 64B)
  ushort* A1 = (ushort*)(smem + 8192);
  ushort* B0 = (ushort*)(smem + 16384);       // 4 KB bf16 each (64 rows x 64B)
  ushort* B1 = (ushort*)(smem + 20480);
  float* invml = (float*)(smem + 24576);      // 256 B

  int tid = threadIdx.x;
  int lane = tid & 63, wave = tid >> 6;
  int wr = (wave >> 1) * 64, wc = (wave & 1) * 32;
  int l15 = lane & 15, lch = lane >> 4;
  int rgrp = lch << 2;

  // ---- A staging via DMA (bf16 Fb): linear dest + pre-swizzled source ----
  int srowA = wave * 32 + (lane >> 2);
  int scolA = ((lane & 3) ^ ((lane >> 3) & 3)) * 8;
  const ushort* gA0 = Fk + (size_t)(bm0 + srowA) * DIM + scolA;
  const ushort* gA1 = gA0 + (size_t)16 * DIM;
  const int loA = wave * 32 * GBK;

  // ---- B reg staging: thread t -> row tid>>2, eighth (tid&3)*8 floats ----
  int rB = tid >> 2, hB = tid & 3;
  const float4* gBp =
      reinterpret_cast<const float4*>(Mk + (size_t)(bn0 + rB) * DIM + hB * 8);
  int wb0 = swz(rB * 64 + hB * 16);       // both-sides swizzled ds_write addr

  // ---- fragment read offsets (K-invariant, swizzled, bf16 both) ----
  int aoff[4], boff[2];
#pragma unroll
  for (int i = 0; i < 4; ++i)
    aoff[i] = swz((wr + i * 16 + l15) * 64 + lch * 16);
#pragma unroll
  for (int j = 0; j < 2; ++j)
    boff[j] = swz((wc + j * 16 + l15) * 64 + lch * 16);

  f32x4 acc[4][2];
#pragma unroll
  for (int i = 0; i < 4; ++i)
#pragma unroll
    for (int j = 0; j < 2; ++j) acc[i][j] = (f32x4){0.f, 0.f, 0.f, 0.f};
  float4 bq0, bq1;            // single B reg set (static names, rule #20)
  float sq = 0.f;             // per-thread sumsq of its B eighth-row

#define LOADB(t)                 \
  do {                           \
    bq0 = gBp[(t) * 8 + 0];      \
    bq1 = gBp[(t) * 8 + 1];      \
  } while (0)

#define DMA_A(t, Ad)                                   \
  do {                                                 \
    gld_lds16(gA0 + (t) * GBK, (Ad) + loA);            \
    gld_lds16(gA1 + (t) * GBK, (Ad) + loA + 16 * GBK); \
  } while (0)

#define WRITEB(Bb)                                                          \
  do {                                                                     \
    sq = fmaf(bq0.x, bq0.x, sq); sq = fmaf(bq0.y, bq0.y, sq);              \
    sq = fmaf(bq0.z, bq0.z, sq); sq = fmaf(bq0.w, bq0.w, sq);              \
    sq = fmaf(bq1.x, bq1.x, sq); sq = fmaf(bq1.y, bq1.y, sq);              \
    sq = fmaf(bq1.z, bq1.z, sq); sq = fmaf(bq1.w, bq1.w, sq);              \
    uint4 w0;                                                              \
    w0.x = cvt2(bq0.x, bq0.y); w0.y = cvt2(bq0.z, bq0.w);                  \
    w0.z = cvt2(bq1.x, bq1.y); w0.w = cvt2(bq1.z, bq1.w);                  \
    *reinterpret_cast<uint4*>((char*)(Bb) + wb0) = w0;                     \
  } while (0)

#define COMPUTE(Ab, Bb)                                                        \
  do {                                                                         \
    bf16x8 af[4], bfr[2];                                                      \
    _Pragma("unroll") for (int i = 0; i < 4; ++i)                              \
        af[i] = *reinterpret_cast<const bf16x8*>((const char*)(Ab) + aoff[i]); \
    _Pragma("unroll") for (int j = 0; j < 2; ++j)                              \
        bfr[j] = *reinterpret_cast<const bf16x8*>((const char*)(Bb) + boff[j]);\
    _Pragma("unroll") for (int i = 0; i < 4; ++i)                              \
        _Pragma("unroll") for (int j = 0; j < 2; ++j) acc[i][j] =              \
            __builtin_amdgcn_mfma_f32_16x16x32_bf16(af[i], bfr[j], acc[i][j],  \
                                                    0, 0, 0);                  \
  } while (0)

#define VMW0 asm volatile("s_waitcnt vmcnt(0)" ::: "memory")
#define LGKM0 asm volatile("s_waitcnt lgkmcnt(0)" ::: "memory")
#define BARR __builtin_amdgcn_s_barrier()
#define SB0 __builtin_amdgcn_sched_barrier(0)

  // prologue (r10 exact)
  LOADB(0); DMA_A(0, A0);
  VMW0; SB0;
  WRITEB(B0);
  LOADB(1); DMA_A(1, A1);
  LGKM0; BARR; SB0;

#pragma unroll
  for (int t = 0; t < NKT; ++t) {
    const ushort* Ab = (t & 1) ? A1 : A0;
    const ushort* Bb = (t & 1) ? B1 : B0;
    COMPUTE(Ab, Bb);
    if (t < NKT - 1) {
      VMW0; BARR; SB0;          // regs(t+1)+DMA(t+1) landed; all reads of [t&1] done
      ushort* Bw = (t & 1) ? B0 : B1;   // (t+1)&1
      WRITEB(Bw);
      if (t < NKT - 2) {
        LOADB(t + 2);
        ushort* Ad = (t & 1) ? A1 : A0;  // (t+2)&1 == t&1
        DMA_A(t + 2, Ad);
      }
      LGKM0; BARR; SB0;         // own ds_writes visible; loads stay in flight
    }
  }

  // ---- invM from reg-accumulated sumsq (each element counted once) ----
  __syncthreads();
  {
    float s2 = sq;
    s2 += __shfl_xor(s2, 1);
    s2 += __shfl_xor(s2, 2);    // reduce over the 4 eighth-row threads
    if (hB == 0) {
      double inv = 1.0 / fmax(sqrt((double)s2), 1e-12);
      invml[rB] = (float)inv;
      if (bm0 == 0) invMg[(size_t)k * NMEM + bn0 + rB] = inv;
    }
  }
  __syncthreads();

  // ---------- epilogue ----------
  size_t kb = (size_t)k * BATCH;
  float fi[4][4];
#pragma unroll
  for (int i = 0; i < 4; ++i)
#pragma unroll
    for (int r = 0; r < 4; ++r)
      fi[i][r] = (float)invF[kb + bm0 + wr + i * 16 + rgrp + r];
  float im[2];
#pragma unroll
  for (int j = 0; j < 2; ++j) im[j] = invml[wc + j * 16 + l15];

  // soft zero-block (coalesced float4)
  {
    const f32x4 z = (f32x4){0.f, 0.f, 0.f, 0.f};
#pragma unroll
    for (int p = 0; p < 8; ++p) {
      int u = p * 256 + tid;
      int row = u >> 4, unit = u & 15;
      *reinterpret_cast<f32x4*>(soft + (kb + bm0 + row) * NMEM + bn0 + unit * 4) = z;
    }
  }

  // 4 quarters of 32 rows x 64 cols: acc -> chunk -> coalesced store + top-4
  float* chunk = (float*)smem;                  // 32*68*4 = 8704 B
  float2* lists = (float2*)(smem + 12288);      // 32*8*4*8 = 8192 B (invml safe)
#pragma unroll
  for (int qt = 0; qt < 4; ++qt) {
    __syncthreads();
    if (wr == (qt >> 1) * 64) {
      const int ibase = (qt & 1) * 2;
#pragma unroll
      for (int ii = 0; ii < 2; ++ii) {
        const int i = ibase + ii;
        int rc0 = ii * 16 + rgrp;
#pragma unroll
        for (int j = 0; j < 2; ++j)
#pragma unroll
          for (int r = 0; r < 4; ++r)
            chunk[(rc0 + r) * CHS + wc + j * 16 + l15] =
                acc[i][j][r] * fi[i][r] * im[j];
      }
    }
    __syncthreads();
    int grow = bm0 + qt * 32;
    // coalesced sim store: 32 rows x 16 f32x4 units = 512 units / 256 thr
#pragma unroll
    for (int uu = 0; uu < 2; ++uu) {
      int u = uu * 256 + tid;
      int rc = u >> 4, cu = u & 15;
      f32x4 v = *reinterpret_cast<const f32x4*>(chunk + rc * CHS + cu * 4);
      *reinterpret_cast<f32x4*>(sim + (kb + grow + rc) * NMEM + bn0 + cu * 4) = v;
    }
    // scan: 8 threads/row, 8 cols each (stride 8)
    int rc = tid >> 3, q8 = tid & 7;
    float v4[4] = {-INFINITY, -INFINITY, -INFINITY, -INFINITY};
    int i4[4] = {0, 0, 0, 0};
#pragma unroll
    for (int j = 0; j < 8; ++j) {
      int cc = q8 + 8 * j;
      float v = chunk[rc * CHS + cc];
      if (v > v4[3]) {
        v4[3] = v; i4[3] = cc;
        if (v4[3] > v4[2]) { float t = v4[3]; v4[3] = v4[2]; v4[2] = t; int s = i4[3]; i4[3] = i4[2]; i4[2] = s; }
        if (v4[2] > v4[1]) { float t = v4[2]; v4[2] = v4[1]; v4[1] = t; int s = i4[2]; i4[2] = i4[1]; i4[1] = s; }
        if (v4[1] > v4[0]) { float t = v4[1]; v4[1] = v4[0]; v4[0] = t; int s = i4[1]; i4[1] = i4[0]; i4[0] = s; }
      }
    }
#pragma unroll
    for (int s = 0; s < 4; ++s)
      lists[(rc * 8 + q8) * 4 + s] = make_float2(v4[s], __builtin_bit_cast(float, i4[s]));
    __syncthreads();
    if (q8 == 0) {
      float mv[4] = {-INFINITY, -INFINITY, -INFINITY, -INFINITY};
      int mi[4] = {0, 0, 0, 0};
#pragma unroll
      for (int e = 0; e < 32; ++e) {
        float2 pe = lists[rc * 32 + e];
        float v = pe.x; int ix = __builtin_bit_cast(int, pe.y);
        if (v > mv[3]) {
          mv[3] = v; mi[3] = ix;
          if (mv[3] > mv[2]) { float t = mv[3]; mv[3] = mv[2]; mv[2] = t; int s = mi[3]; mi[3] = mi[2]; mi[2] = s; }
          if (mv[2] > mv[1]) { float t = mv[2]; mv[2] = mv[1]; mv[1] = t; int s = mi[2]; mi[2] = mi[1]; mi[1] = s; }
          if (mv[1] > mv[0]) { float t = mv[1]; mv[1] = mv[0]; mv[0] = t; int s = mi[1]; mi[1] = mi[0]; mi[0] = s; }
        }
      }
      float2* Prow = P + ((size_t)(kb + grow + rc) * NXBLK + ntile) * 4;
#pragma unroll
      for (int s = 0; s < 4; ++s)
        Prow[s] = make_float2(mv[s], __builtin_bit_cast(float, mi[s] + bn0));
    }
  }
#undef LOADB
#undef DMA_A
#undef WRITEB
#undef COMPUTE
#undef VMW0
#undef LGKM0
#undef BARR
#undef SB0
}

// ---------------- merge partials + fp64 refine + softmax + entropy ----------

__global__ __launch_bounds__(256) void merge_kernel(
    const float* __restrict__ F, const float* __restrict__ M,
    const double* __restrict__ invF, const double* __restrict__ invM,
    const float2* __restrict__ P, float* __restrict__ soft,
    float* __restrict__ ent) {
  int kb = blockIdx.x;  // 0..1535
  int k = kb / BATCH;
  int tid = threadIdx.x;
  float* orow = soft + (size_t)kb * NMEM;

  __shared__ float sval[2048];
  __shared__ int   sidx[2048];
  const float2* Prow = P + (size_t)kb * NXBLK * 4;
#pragma unroll
  for (int j = 0; j < 8; ++j) {
    float2 e = Prow[tid * 8 + j];
    sval[tid * 8 + j] = e.x;
    sidx[tid * 8 + j] = __builtin_bit_cast(int, e.y);
  }
  __syncthreads();

  __shared__ float rv[256]; __shared__ int rp[256];
  __shared__ float cand_v[8]; __shared__ int cand_i[8];
  for (int r = 0; r < 8; ++r) {
    float best = -INFINITY; int bpos = tid * 8;
#pragma unroll
    for (int j = 0; j < 8; ++j) {
      float v = sval[tid * 8 + j];
      if (v > best) { best = v; bpos = tid * 8 + j; }
    }
    rv[tid] = best; rp[tid] = bpos;
    __syncthreads();
    for (int st = 128; st > 0; st >>= 1) {
      if (tid < st && rv[tid + st] > rv[tid]) { rv[tid] = rv[tid + st]; rp[tid] = rp[tid + st]; }
      __syncthreads();
    }
    if (tid == 0) {
      cand_v[r] = rv[0]; cand_i[r] = sidx[rp[0]];
      sval[rp[0]] = -INFINITY;
    }
    __syncthreads();
  }

  // fp64 refinement of the 8 candidates (exact re-ranking at the 5/6 boundary)
  __shared__ double dred[256];
  __shared__ double cval[8];
  const float* fr = F + (size_t)kb * DIM;
  double invf = invF[kb];
  for (int c = 0; c < 8; ++c) {
    const float* mr = M + ((size_t)k * NMEM + cand_i[c]) * DIM;
    double s = 0.0;
    for (int d = tid; d < DIM; d += 256) s += (double)fr[d] * (double)mr[d];
    dred[tid] = s; __syncthreads();
    for (int st = 128; st > 0; st >>= 1) {
      if (tid < st) dred[tid] += dred[tid + st];
      __syncthreads();
    }
    if (tid == 0) cval[c] = dred[0] * invf * invM[(size_t)k * NMEM + cand_i[c]];
    __syncthreads();
  }

  if (tid == 0) {
    int ord[8];
    for (int i = 0; i < 8; ++i) ord[i] = i;
    for (int i = 0; i < 5; ++i) {
      int best = i;
      for (int j = i + 1; j < 8; ++j) {
        float fa = (float)cval[ord[j]], fb = (float)cval[ord[best]];
        bool better = (fa != fb) ? (fa > fb) : (cand_i[ord[j]] < cand_i[ord[best]]);
        if (better) best = j;
      }
      int t = ord[i]; ord[i] = ord[best]; ord[best] = t;
    }
    float v5[5]; int i5[5];
    float vmax = -INFINITY;
    for (int i = 0; i < 5; ++i) {
      v5[i] = cand_v[ord[i]]; i5[i] = cand_i[ord[i]];
      vmax = fmaxf(vmax, v5[i]);
    }
    float e[5], Z = 0.f;
    float xm = vmax / 3.0f;
    for (int i = 0; i < 5; ++i) { e[i] = expf(v5[i] / 3.0f - xm); Z += e[i]; }
    float ent_s = 0.f;
    for (int i = 0; i < 5; ++i) {
      float p = e[i] / Z;
      orow[i5[i]] = p;
      ent_s += p * logf(p);
    }
    float tiny = 1e-8f * logf(1e-8f);
    ent[kb] = -(ent_s + (float)(NMEM - 5) * tiny);
  }
}

// ---------------- entropy weights ----------------

__global__ __launch_bounds__(256) void w_kernel(const float* __restrict__ ent,
                                                float* __restrict__ wout) {
  int k = blockIdx.x; int tid = threadIdx.x;
  float e = ent[k * BATCH + tid];
  float wv = expf(-e);
  __shared__ float red[256];
  red[tid] = wv; __syncthreads();
  for (int st = 128; st > 0; st >>= 1) {
    if (tid < st) red[tid] += red[tid + st];
    __syncthreads();
  }
  float mean = red[0] / (float)BATCH;
  wout[k * BATCH + tid] = wv / (mean + 1e-8f);
}

// ---------------- launch ----------------

extern "C" void kernel_launch(void* const* d_in, const int* in_sizes, int n_in,
                              void* d_out, int out_size, void* d_ws, size_t ws_size,
                              hipStream_t stream) {
  (void)in_sizes; (void)n_in; (void)out_size; (void)ws_size;
  const float* F = (const float*)d_in[0];   // [KP, BATCH, DIM] fp32
  const float* M = (const float*)d_in[1];   // [KP, NMEM, DIM] fp32
  float* out = (float*)d_out;
  size_t simsz = (size_t)KP * BATCH * NMEM;
  float* soft = out;
  float* sim = out + simsz;
  float* wout = out + 2 * simsz;

  // workspace: Fb bf16 (2.4 MB) + invM f64 + invF f64 + ent + P (~25 MB)
  ushort* Fb = (ushort*)d_ws;                               // KP*BATCH*DIM bf16
  double* invM = (double*)(Fb + (size_t)KP * BATCH * DIM);  // KP*NMEM f64
  double* invF = invM + (size_t)KP * NMEM;                  // KP*BATCH f64
  float* ent = (float*)(invF + KP * BATCH);                 // KP*BATCH f32
  float2* P = (float2*)(ent + NROWS);                       // NROWS*NXBLK*4 float2

  prep_kernel<<<KP * BATCH / 4, 256, 0, stream>>>(F, Fb, invF, KP * BATCH);
  gemm_kernel<<<(BATCH / GBM) * (NMEM / GBN) * KP, 256, 0, stream>>>(M, Fb, invF, invM, sim, soft, P);
  merge_kernel<<<NROWS, 256, 0, stream>>>(F, M, invF, invM, P, soft, ent);
  w_kernel<<<KP, 256, 0, stream>>>(ent, wout);
}

// Round 19
// 362.703 us; speedup vs baseline: 1.4403x; 1.1275x over previous
//
#include <hip/hip_runtime.h>
#include <hip/hip_bf16.h>
#include <math.h>

#define KP 6
#define BATCH 256
#define DIM 768
#define NMEM 32768
#define NXBLK (NMEM / 128)   // col-blocks per row = 256
#define NROWS (KP * BATCH)   // 1536

typedef __attribute__((ext_vector_type(8))) short bf16x8;
typedef __attribute__((ext_vector_type(4))) float f32x4;

__device__ inline uint bf16rne(float x) {
  uint u = __builtin_bit_cast(uint, x);
  return (u + 0x7fffu + ((u >> 16) & 1u)) >> 16;
}
__device__ inline uint pk2(float lo, float hi) {
  return bf16rne(lo) | (bf16rne(hi) << 16);
}
// packed cvt via casts (clang emits v_cvt_pk_bf16_f32 pairs; m240: don't hand-asm)
__device__ inline uint cvt2(float lo, float hi) {
  return (uint)__builtin_bit_cast(ushort, __float2bfloat16(lo)) |
         ((uint)__builtin_bit_cast(ushort, __float2bfloat16(hi)) << 16);
}
// bf16 tile swizzle (64B rows): flip 16B-unit bits 4-5 with row bits 1-2.
__device__ inline int swz(int b) { return b ^ (((b >> 7) & 3) << 4); }

__device__ inline void gld_lds16(const void* g, void* l) {
  __builtin_amdgcn_global_load_lds(
      (const __attribute__((address_space(1))) void*)g,
      (__attribute__((address_space(3))) void*)l, 16, 0, 0);
}

// ---------------- prep (F only): fp64 inv-norms + bf16 copy ----------------

__global__ __launch_bounds__(256) void prep_kernel(const float* __restrict__ X,
                                                   ushort* __restrict__ Xb,
                                                   double* __restrict__ invX,
                                                   int nrows) {
  int wid = threadIdx.x >> 6, lane = threadIdx.x & 63;
  int row = blockIdx.x * 4 + wid;
  if (row >= nrows) return;
  const float* x = X + (size_t)row * DIM;
  ushort* xb = Xb + (size_t)row * DIM;
  double s = 0.0;
#pragma unroll
  for (int i = 0; i < 3; ++i) {
    int d = i * 256 + lane * 4;
    float4 v = *reinterpret_cast<const float4*>(x + d);
    s += (double)v.x * v.x + (double)v.y * v.y;
    s += (double)v.z * v.z + (double)v.w * v.w;
    uint2 p; p.x = pk2(v.x, v.y); p.y = pk2(v.z, v.w);
    *reinterpret_cast<uint2*>(xb + d) = p;
  }
  for (int off = 32; off > 0; off >>= 1) s += __shfl_down(s, off);
  if (lane == 0) invX[row] = 1.0 / fmax(sqrt(s), 1e-12);
}

// ------ fused GEMM (r10 tile/staging EXACT). r19: launch_bounds(256,2) so the
// ------ unified VGPR+AGPR budget is 256 (the (256,4)=128 cap caused every
// ------ r11-r18 "spill cliff") + the counted-vmcnt schedule: VMW2 retires
// ------ only B-regs (A-DMA stays in flight), WRITEB/LOADB overlap the
// ------ barrier, VMW6 retires DMA(t+1) after issuing DMA(t+2). ----

#define GBM 128
#define GBN 128
#define GBK 32
#define NKT (DIM / GBK)  // 24
#define CHS 132          // epilogue chunk row stride in floats

__global__ __launch_bounds__(256, 2) void gemm_kernel(
    const float* __restrict__ M, const ushort* __restrict__ Fb,
    const double* __restrict__ invF, double* __restrict__ invMg,
    float* __restrict__ sim, float* __restrict__ soft, float2* __restrict__ P) {
  // bijective XCD swizzle: 3072 wg = 8 xcd x 384; m-tile pair adjacent per XCD
  int lin = blockIdx.x;
  int wg = (lin & 7) * 384 + (lin >> 3);
  int k = wg >> 9;
  int bm0 = (wg & 1) * GBM;
  int ntile = (wg >> 1) & 255;
  int bn0 = ntile * GBN;
  const ushort* Fk = Fb + (size_t)k * BATCH * DIM;
  const float* Mk = M + (size_t)k * NMEM * DIM;

  __shared__ __align__(16) char smem[33280];
  ushort* A0 = (ushort*)smem;                 // 8 KB bf16 each
  ushort* A1 = (ushort*)(smem + 8192);
  ushort* B0 = (ushort*)(smem + 16384);
  ushort* B1 = (ushort*)(smem + 24576);
  float* invml = (float*)(smem + 32768);      // 512 B

  int tid = threadIdx.x;
  int lane = tid & 63, wave = tid >> 6;
  int wr = (wave >> 1) * 64, wc = (wave & 1) * 64;
  int l15 = lane & 15, lch = lane >> 4;
  int rgrp = lch << 2;

  // ---- A staging via DMA (bf16 Fb): linear dest + pre-swizzled source ----
  int srowA = wave * 32 + (lane >> 2);
  int scolA = ((lane & 3) ^ ((lane >> 3) & 3)) * 8;
  const ushort* gA0 = Fk + (size_t)(bm0 + srowA) * DIM + scolA;
  const ushort* gA1 = gA0 + (size_t)16 * DIM;
  const int loA = wave * 32 * GBK;

  // ---- B reg staging: thread t -> row tid>>1, half (tid&1)*16 floats ----
  int rB = tid >> 1, hB = tid & 1;
  const float4* gBp =
      reinterpret_cast<const float4*>(Mk + (size_t)(bn0 + rB) * DIM + hB * 16);
  int wb0 = swz(rB * 64 + hB * 32);       // both-sides swizzled ds_write addrs
  int wb1 = swz(rB * 64 + hB * 32 + 16);  // (8 lanes/bank-quad: conflict-free)

  // ---- fragment read offsets (K-invariant, swizzled, bf16 both) ----
  int aoff[4], boff[4];
#pragma unroll
  for (int i = 0; i < 4; ++i) {
    aoff[i] = swz((wr + i * 16 + l15) * 64 + lch * 16);
    boff[i] = swz((wc + i * 16 + l15) * 64 + lch * 16);
  }

  f32x4 acc[4][4];
#pragma unroll
  for (int i = 0; i < 4; ++i)
#pragma unroll
    for (int j = 0; j < 4; ++j) acc[i][j] = (f32x4){0.f, 0.f, 0.f, 0.f};
  float4 bq0, bq1, bq2, bq3;  // single B reg set (static names, rule #20)
  float sq = 0.f;             // per-thread sumsq of its B half-row

#define LOADB(t)                 \
  do {                           \
    bq0 = gBp[(t) * 8 + 0];      \
    bq1 = gBp[(t) * 8 + 1];      \
    bq2 = gBp[(t) * 8 + 2];      \
    bq3 = gBp[(t) * 8 + 3];      \
  } while (0)

#define DMA_A(t, Ad)                                   \
  do {                                                 \
    gld_lds16(gA0 + (t) * GBK, (Ad) + loA);            \
    gld_lds16(gA1 + (t) * GBK, (Ad) + loA + 16 * GBK); \
  } while (0)

#define WRITEB(Bb)                                                          \
  do {                                                                     \
    sq = fmaf(bq0.x, bq0.x, sq); sq = fmaf(bq0.y, bq0.y, sq);              \
    sq = fmaf(bq0.z, bq0.z, sq); sq = fmaf(bq0.w, bq0.w, sq);              \
    sq = fmaf(bq1.x, bq1.x, sq); sq = fmaf(bq1.y, bq1.y, sq);              \
    sq = fmaf(bq1.z, bq1.z, sq); sq = fmaf(bq1.w, bq1.w, sq);              \
    sq = fmaf(bq2.x, bq2.x, sq); sq = fmaf(bq2.y, bq2.y, sq);              \
    sq = fmaf(bq2.z, bq2.z, sq); sq = fmaf(bq2.w, bq2.w, sq);              \
    sq = fmaf(bq3.x, bq3.x, sq); sq = fmaf(bq3.y, bq3.y, sq);              \
    sq = fmaf(bq3.z, bq3.z, sq); sq = fmaf(bq3.w, bq3.w, sq);              \
    uint4 w0, w1;                                                          \
    w0.x = cvt2(bq0.x, bq0.y); w0.y = cvt2(bq0.z, bq0.w);                  \
    w0.z = cvt2(bq1.x, bq1.y); w0.w = cvt2(bq1.z, bq1.w);                  \
    w1.x = cvt2(bq2.x, bq2.y); w1.y = cvt2(bq2.z, bq2.w);                  \
    w1.z = cvt2(bq3.x, bq3.y); w1.w = cvt2(bq3.z, bq3.w);                  \
    *reinterpret_cast<uint4*>((char*)(Bb) + wb0) = w0;                     \
    *reinterpret_cast<uint4*>((char*)(Bb) + wb1) = w1;                     \
  } while (0)

#define COMPUTE(Ab, Bb)                                                        \
  do {                                                                         \
    bf16x8 af[4], bfr[4];                                                      \
    _Pragma("unroll") for (int i = 0; i < 4; ++i) {                            \
      af[i] = *reinterpret_cast<const bf16x8*>((const char*)(Ab) + aoff[i]);   \
      bfr[i] = *reinterpret_cast<const bf16x8*>((const char*)(Bb) + boff[i]);  \
    }                                                                          \
    _Pragma("unroll") for (int i = 0; i < 4; ++i)                              \
        _Pragma("unroll") for (int j = 0; j < 4; ++j) acc[i][j] =              \
            __builtin_amdgcn_mfma_f32_16x16x32_bf16(af[i], bfr[j], acc[i][j],  \
                                                    0, 0, 0);                  \
  } while (0)

#define VMW2 asm volatile("s_waitcnt vmcnt(2)" ::: "memory")
#define VMW6 asm volatile("s_waitcnt vmcnt(6)" ::: "memory")
#define VMW0 asm volatile("s_waitcnt vmcnt(0)" ::: "memory")
#define LGKM0 asm volatile("s_waitcnt lgkmcnt(0)" ::: "memory")
#define BARR __builtin_amdgcn_s_barrier()
#define SB0 __builtin_amdgcn_sched_barrier(0)

  // prologue: queue = [B0:4, A0:2]
  LOADB(0); DMA_A(0, A0);
  VMW2; SB0;                     // retire B0 regs (A0 DMA in flight)
  WRITEB(B0);
  LOADB(1); DMA_A(1, A1);        // queue [A0:2, B1:4, A1:2] = 8
  VMW6; SB0;                     // retire A0 DMA
  LGKM0; BARR; SB0;              // B0 visible; entry invariant [B1:4, A1:2]

  // steady iter t: entry queue [B(t+1):4, A(t+1):2].
  // VMW2: B(t+1) regs ready, A-DMA(t+1) in flight (T4: never drain mid-loop).
  // WRITEB targets B[(t+1)&1], last read at t-1 behind a barrier -> safe; its
  // VALU overlaps lagging waves' MFMAs. BARR before DMA_A(t+2) (dest=A[t&1],
  // all waves' COMPUTE(t) reads done). VMW6 retires DMA_A(t+1) only.
#pragma unroll
  for (int t = 0; t < NKT; ++t) {
    const ushort* Ab = (t & 1) ? A1 : A0;
    const ushort* Bb = (t & 1) ? B1 : B0;
    COMPUTE(Ab, Bb);
    if (t < NKT - 1) {
      VMW2; SB0;
      ushort* Bw = (t & 1) ? B0 : B1;   // (t+1)&1
      WRITEB(Bw);
      if (t < NKT - 2) LOADB(t + 2);
      BARR;
      if (t < NKT - 2) {
        ushort* Ad = (t & 1) ? A1 : A0;  // (t+2)&1 == t&1
        DMA_A(t + 2, Ad);
        VMW6; SB0;
      } else {
        VMW0; SB0;                       // tail: drain DMA_A(23)
      }
      LGKM0; BARR; SB0;
    }
  }

  // ---- invM from reg-accumulated sumsq (each element counted once) ----
  __syncthreads();
  {
    float s2 = sq + __shfl_xor(sq, 1);  // pair (2r, 2r+1) -> full row r
    if (hB == 0) {
      double inv = 1.0 / fmax(sqrt((double)s2), 1e-12);
      invml[rB] = (float)inv;
      if (bm0 == 0) invMg[(size_t)k * NMEM + bn0 + rB] = inv;
    }
  }
  __syncthreads();

  // ---------- epilogue (r10 exact) ----------
  size_t kb = (size_t)k * BATCH;
  float fi[4][4];
#pragma unroll
  for (int i = 0; i < 4; ++i)
#pragma unroll
    for (int r = 0; r < 4; ++r)
      fi[i][r] = (float)invF[kb + bm0 + wr + i * 16 + rgrp + r];
  float im[4];
#pragma unroll
  for (int j = 0; j < 4; ++j) im[j] = invml[wc + j * 16 + l15];

  // soft zero-block (coalesced float4); top-5 scatter happens in merge
  {
    const f32x4 z = (f32x4){0.f, 0.f, 0.f, 0.f};
#pragma unroll
    for (int p = 0; p < 16; ++p) {
      int u = p * 256 + tid;
      int row = u >> 5, unit = u & 31;
      *reinterpret_cast<f32x4*>(soft + (kb + bm0 + row) * NMEM + bn0 + unit * 4) = z;
    }
  }

  // 4 quarters of 32 rows: acc -> LDS chunk -> coalesced sim store + top-4 scan
  // qt loop fully unrolled (rule #20: runtime-indexed acc -> scratch disaster)
  float* chunk = (float*)smem;                  // 16896 B
  float2* lists = (float2*)(smem + 24576);      // 8192 B
#pragma unroll
  for (int qt = 0; qt < 4; ++qt) {
    __syncthreads();
    if (wr == (qt >> 1) * 64) {
      const int ibase = (qt & 1) * 2;
#pragma unroll
      for (int ii = 0; ii < 2; ++ii) {
        const int i = ibase + ii;
        int rc0 = ii * 16 + rgrp;
#pragma unroll
        for (int j = 0; j < 4; ++j)
#pragma unroll
          for (int r = 0; r < 4; ++r)
            chunk[(rc0 + r) * CHS + wc + j * 16 + l15] =
                acc[i][j][r] * fi[i][r] * im[j];
      }
    }
    __syncthreads();
    int grow = bm0 + qt * 32;
#pragma unroll
    for (int uu = 0; uu < 4; ++uu) {
      int u = uu * 256 + tid;
      int rc = u >> 5, cu = u & 31;
      f32x4 v = *reinterpret_cast<const f32x4*>(chunk + rc * CHS + cu * 4);
      *reinterpret_cast<f32x4*>(sim + (kb + grow + rc) * NMEM + bn0 + cu * 4) = v;
    }
    int rc = tid >> 3, q8 = tid & 7;
    float v4[4] = {-INFINITY, -INFINITY, -INFINITY, -INFINITY};
    int i4[4] = {0, 0, 0, 0};
#pragma unroll
    for (int j = 0; j < 16; ++j) {
      int cc = q8 + 8 * j;
      float v = chunk[rc * CHS + cc];
      if (v > v4[3]) {
        v4[3] = v; i4[3] = cc;
        if (v4[3] > v4[2]) { float t = v4[3]; v4[3] = v4[2]; v4[2] = t; int s = i4[3]; i4[3] = i4[2]; i4[2] = s; }
        if (v4[2] > v4[1]) { float t = v4[2]; v4[2] = v4[1]; v4[1] = t; int s = i4[2]; i4[2] = i4[1]; i4[1] = s; }
        if (v4[1] > v4[0]) { float t = v4[1]; v4[1] = v4[0]; v4[0] = t; int s = i4[1]; i4[1] = i4[0]; i4[0] = s; }
      }
    }
#pragma unroll
    for (int s = 0; s < 4; ++s)
      lists[(rc * 8 + q8) * 4 + s] = make_float2(v4[s], __builtin_bit_cast(float, i4[s]));
    __syncthreads();
    if (q8 == 0) {
      float mv[4] = {-INFINITY, -INFINITY, -INFINITY, -INFINITY};
      int mi[4] = {0, 0, 0, 0};
#pragma unroll
      for (int e = 0; e < 32; ++e) {
        float2 pe = lists[rc * 32 + e];
        float v = pe.x; int ix = __builtin_bit_cast(int, pe.y);
        if (v > mv[3]) {
          mv[3] = v; mi[3] = ix;
          if (mv[3] > mv[2]) { float t = mv[3]; mv[3] = mv[2]; mv[2] = t; int s = mi[3]; mi[3] = mi[2]; mi[2] = s; }
          if (mv[2] > mv[1]) { float t = mv[2]; mv[2] = mv[1]; mv[1] = t; int s = mi[2]; mi[2] = mi[1]; mi[1] = s; }
          if (mv[1] > mv[0]) { float t = mv[1]; mv[1] = mv[0]; mv[0] = t; int s = mi[1]; mi[1] = mi[0]; mi[0] = s; }
        }
      }
      float2* Prow = P + ((size_t)(kb + grow + rc) * NXBLK + ntile) * 4;
#pragma unroll
      for (int s = 0; s < 4; ++s)
        Prow[s] = make_float2(mv[s], __builtin_bit_cast(float, mi[s] + bn0));
    }
  }
#undef LOADB
#undef DMA_A
#undef WRITEB
#undef COMPUTE
#undef VMW2
#undef VMW6
#undef VMW0
#undef LGKM0
#undef BARR
#undef SB0
}

// ---------------- merge partials + fp64 refine + softmax + entropy ----------

__global__ __launch_bounds__(256) void merge_kernel(
    const float* __restrict__ F, const float* __restrict__ M,
    const double* __restrict__ invF, const double* __restrict__ invM,
    const float2* __restrict__ P, float* __restrict__ soft,
    float* __restrict__ ent) {
  int kb = blockIdx.x;  // 0..1535
  int k = kb / BATCH;
  int tid = threadIdx.x;
  float* orow = soft + (size_t)kb * NMEM;

  __shared__ float sval[1024];
  __shared__ int   sidx[1024];
  const float2* Prow = P + (size_t)kb * NXBLK * 4;
#pragma unroll
  for (int j = 0; j < 4; ++j) {
    float2 e = Prow[tid * 4 + j];
    sval[tid * 4 + j] = e.x;
    sidx[tid * 4 + j] = __builtin_bit_cast(int, e.y);
  }
  __syncthreads();

  __shared__ float rv[256]; __shared__ int rp[256];
  __shared__ float cand_v[8]; __shared__ int cand_i[8];
  for (int r = 0; r < 8; ++r) {
    float best = -INFINITY; int bpos = tid * 4;
#pragma unroll
    for (int j = 0; j < 4; ++j) {
      float v = sval[tid * 4 + j];
      if (v > best) { best = v; bpos = tid * 4 + j; }
    }
    rv[tid] = best; rp[tid] = bpos;
    __syncthreads();
    for (int st = 128; st > 0; st >>= 1) {
      if (tid < st && rv[tid + st] > rv[tid]) { rv[tid] = rv[tid + st]; rp[tid] = rp[tid + st]; }
      __syncthreads();
    }
    if (tid == 0) {
      cand_v[r] = rv[0]; cand_i[r] = sidx[rp[0]];
      sval[rp[0]] = -INFINITY;
    }
    __syncthreads();
  }

  // fp64 refinement of the 8 candidates (exact re-ranking at the 5/6 boundary)
  __shared__ double dred[256];
  __shared__ double cval[8];
  const float* fr = F + (size_t)kb * DIM;
  double invf = invF[kb];
  for (int c = 0; c < 8; ++c) {
    const float* mr = M + ((size_t)k * NMEM + cand_i[c]) * DIM;
    double s = 0.0;
    for (int d = tid; d < DIM; d += 256) s += (double)fr[d] * (double)mr[d];
    dred[tid] = s; __syncthreads();
    for (int st = 128; st > 0; st >>= 1) {
      if (tid < st) dred[tid] += dred[tid + st];
      __syncthreads();
    }
    if (tid == 0) cval[c] = dred[0] * invf * invM[(size_t)k * NMEM + cand_i[c]];
    __syncthreads();
  }

  if (tid == 0) {
    int ord[8];
    for (int i = 0; i < 8; ++i) ord[i] = i;
    for (int i = 0; i < 5; ++i) {
      int best = i;
      for (int j = i + 1; j < 8; ++j) {
        float fa = (float)cval[ord[j]], fb = (float)cval[ord[best]];
        bool better = (fa != fb) ? (fa > fb) : (cand_i[ord[j]] < cand_i[ord[best]]);
        if (better) best = j;
      }
      int t = ord[i]; ord[i] = ord[best]; ord[best] = t;
    }
    float v5[5]; int i5[5];
    float vmax = -INFINITY;
    for (int i = 0; i < 5; ++i) {
      v5[i] = cand_v[ord[i]]; i5[i] = cand_i[ord[i]];
      vmax = fmaxf(vmax, v5[i]);
    }
    float e[5], Z = 0.f;
    float xm = vmax / 3.0f;
    for (int i = 0; i < 5; ++i) { e[i] = expf(v5[i] / 3.0f - xm); Z += e[i]; }
    float ent_s = 0.f;
    for (int i = 0; i < 5; ++i) {
      float p = e[i] / Z;
      orow[i5[i]] = p;
      ent_s += p * logf(p);
    }
    float tiny = 1e-8f * logf(1e-8f);
    ent[kb] = -(ent_s + (float)(NMEM - 5) * tiny);
  }
}

// ---------------- entropy weights ----------------

__global__ __launch_bounds__(256) void w_kernel(const float* __restrict__ ent,
                                                float* __restrict__ wout) {
  int k = blockIdx.x; int tid = threadIdx.x;
  float e = ent[k * BATCH + tid];
  float wv = expf(-e);
  __shared__ float red[256];
  red[tid] = wv; __syncthreads();
  for (int st = 128; st > 0; st >>= 1) {
    if (tid < st) red[tid] += red[tid + st];
    __syncthreads();
  }
  float mean = red[0] / (float)BATCH;
  wout[k * BATCH + tid] = wv / (mean + 1e-8f);
}

// ---------------- launch ----------------

extern "C" void kernel_launch(void* const* d_in, const int* in_sizes, int n_in,
                              void* d_out, int out_size, void* d_ws, size_t ws_size,
                              hipStream_t stream) {
  (void)in_sizes; (void)n_in; (void)out_size; (void)ws_size;
  const float* F = (const float*)d_in[0];   // [KP, BATCH, DIM] fp32
  const float* M = (const float*)d_in[1];   // [KP, NMEM, DIM] fp32
  float* out = (float*)d_out;
  size_t simsz = (size_t)KP * BATCH * NMEM;
  float* soft = out;
  float* sim = out + simsz;
  float* wout = out + 2 * simsz;

  // workspace: Fb bf16 (2.4 MB) + invM f64 + invF f64 + ent + P (~16 MB)
  ushort* Fb = (ushort*)d_ws;                               // KP*BATCH*DIM bf16
  double* invM = (double*)(Fb + (size_t)KP * BATCH * DIM);  // KP*NMEM f64
  double* invF = invM + (size_t)KP * NMEM;                  // KP*BATCH f64
  float* ent = (float*)(invF + KP * BATCH);                 // KP*BATCH f32
  float2* P = (float2*)(ent + NROWS);                       // NROWS*NXBLK*4 float2

  prep_kernel<<<KP * BATCH / 4, 256, 0, stream>>>(F, Fb, invF, KP * BATCH);
  gemm_kernel<<<(BATCH / GBM) * (NMEM / GBN) * KP, 256, 0, stream>>>(M, Fb, invF, invM, sim, soft, P);
  merge_kernel<<<NROWS, 256, 0, stream>>>(F, M, invF, invM, P, soft, ent);
  w_kernel<<<KP, 256, 0, stream>>>(ent, wout);
}

// Round 20
// 361.050 us; speedup vs baseline: 1.4469x; 1.0046x over previous
//
#include <hip/hip_runtime.h>
#include <hip/hip_bf16.h>
#include <math.h>

#define KP 6
#define BATCH 256
#define DIM 768
#define NMEM 32768
#define NXBLK (NMEM / 128)   // col-blocks per row = 256
#define NROWS (KP * BATCH)   // 1536

typedef __attribute__((ext_vector_type(8))) short bf16x8;
typedef __attribute__((ext_vector_type(4))) float f32x4;

__device__ inline uint bf16rne(float x) {
  uint u = __builtin_bit_cast(uint, x);
  return (u + 0x7fffu + ((u >> 16) & 1u)) >> 16;
}
__device__ inline uint pk2(float lo, float hi) {
  return bf16rne(lo) | (bf16rne(hi) << 16);
}
// packed cvt via casts (clang emits v_cvt_pk_bf16_f32 pairs; m240: don't hand-asm)
__device__ inline uint cvt2(float lo, float hi) {
  return (uint)__builtin_bit_cast(ushort, __float2bfloat16(lo)) |
         ((uint)__builtin_bit_cast(ushort, __float2bfloat16(hi)) << 16);
}
// bf16 tile swizzle (64B rows): flip 16B-unit bits 4-5 with row bits 1-2.
__device__ inline int swz(int b) { return b ^ (((b >> 7) & 3) << 4); }

__device__ inline void gld_lds16(const void* g, void* l) {
  __builtin_amdgcn_global_load_lds(
      (const __attribute__((address_space(1))) void*)g,
      (__attribute__((address_space(3))) void*)l, 16, 0, 0);
}

// ---------------- prep (F only): fp64 inv-norms + bf16 copy ----------------

__global__ __launch_bounds__(256) void prep_kernel(const float* __restrict__ X,
                                                   ushort* __restrict__ Xb,
                                                   double* __restrict__ invX,
                                                   int nrows) {
  int wid = threadIdx.x >> 6, lane = threadIdx.x & 63;
  int row = blockIdx.x * 4 + wid;
  if (row >= nrows) return;
  const float* x = X + (size_t)row * DIM;
  ushort* xb = Xb + (size_t)row * DIM;
  double s = 0.0;
#pragma unroll
  for (int i = 0; i < 3; ++i) {
    int d = i * 256 + lane * 4;
    float4 v = *reinterpret_cast<const float4*>(x + d);
    s += (double)v.x * v.x + (double)v.y * v.y;
    s += (double)v.z * v.z + (double)v.w * v.w;
    uint2 p; p.x = pk2(v.x, v.y); p.y = pk2(v.z, v.w);
    *reinterpret_cast<uint2*>(xb + d) = p;
  }
  for (int off = 32; off > 0; off >>= 1) s += __shfl_down(s, off);
  if (lane == 0) invX[row] = 1.0 / fmax(sqrt(s), 1e-12);
}

// ------ fused GEMM (round-10 exact, twice-validated best: 361.2 µs total).
// ------ B reg-staged (fp32->bf16 cvt + sumsq in write phase), A DMA'd bf16,
// ------ clean bf16 COMPUTE, 32.5KB LDS. PLATEAU NOTE (r11-r19 post-mortems):
// ------ occupancy up (r18) or down-with-headroom (r19), counted vmcnt (r19),
// ------ deeper prefetch (r13), barrier-free (r14), hoisted stage (r15),
// ------ direct-A (r17), BM=256 (r11) — ALL regress or are neutral. The
// ------ residual stall is structural to the barrier-coupled fused staging. --

#define GBM 128
#define GBN 128
#define GBK 32
#define NKT (DIM / GBK)  // 24
#define CHS 132          // epilogue chunk row stride in floats

__global__ __launch_bounds__(256, 4) void gemm_kernel(
    const float* __restrict__ M, const ushort* __restrict__ Fb,
    const double* __restrict__ invF, double* __restrict__ invMg,
    float* __restrict__ sim, float* __restrict__ soft, float2* __restrict__ P) {
  // bijective XCD swizzle: 3072 wg = 8 xcd x 384; m-tile pair adjacent per XCD
  int lin = blockIdx.x;
  int wg = (lin & 7) * 384 + (lin >> 3);
  int k = wg >> 9;
  int bm0 = (wg & 1) * GBM;
  int ntile = (wg >> 1) & 255;
  int bn0 = ntile * GBN;
  const ushort* Fk = Fb + (size_t)k * BATCH * DIM;
  const float* Mk = M + (size_t)k * NMEM * DIM;

  __shared__ __align__(16) char smem[33280];
  ushort* A0 = (ushort*)smem;                 // 8 KB bf16 each
  ushort* A1 = (ushort*)(smem + 8192);
  ushort* B0 = (ushort*)(smem + 16384);
  ushort* B1 = (ushort*)(smem + 24576);
  float* invml = (float*)(smem + 32768);      // 512 B

  int tid = threadIdx.x;
  int lane = tid & 63, wave = tid >> 6;
  int wr = (wave >> 1) * 64, wc = (wave & 1) * 64;
  int l15 = lane & 15, lch = lane >> 4;
  int rgrp = lch << 2;

  // ---- A staging via DMA (bf16 Fb): linear dest + pre-swizzled source ----
  int srowA = wave * 32 + (lane >> 2);
  int scolA = ((lane & 3) ^ ((lane >> 3) & 3)) * 8;
  const ushort* gA0 = Fk + (size_t)(bm0 + srowA) * DIM + scolA;
  const ushort* gA1 = gA0 + (size_t)16 * DIM;
  const int loA = wave * 32 * GBK;

  // ---- B reg staging: thread t -> row tid>>1, half (tid&1)*16 floats ----
  int rB = tid >> 1, hB = tid & 1;
  const float4* gBp =
      reinterpret_cast<const float4*>(Mk + (size_t)(bn0 + rB) * DIM + hB * 16);
  int wb0 = swz(rB * 64 + hB * 32);       // both-sides swizzled ds_write addrs
  int wb1 = swz(rB * 64 + hB * 32 + 16);  // (8 lanes/bank-quad: conflict-free)

  // ---- fragment read offsets (K-invariant, swizzled, bf16 both) ----
  int aoff[4], boff[4];
#pragma unroll
  for (int i = 0; i < 4; ++i) {
    aoff[i] = swz((wr + i * 16 + l15) * 64 + lch * 16);
    boff[i] = swz((wc + i * 16 + l15) * 64 + lch * 16);
  }

  f32x4 acc[4][4];
#pragma unroll
  for (int i = 0; i < 4; ++i)
#pragma unroll
    for (int j = 0; j < 4; ++j) acc[i][j] = (f32x4){0.f, 0.f, 0.f, 0.f};
  float4 bq0, bq1, bq2, bq3;  // static names (rule #20)
  float sq = 0.f;             // per-thread sumsq of its B half-row

#define LOADB(t)                 \
  do {                           \
    bq0 = gBp[(t) * 8 + 0];      \
    bq1 = gBp[(t) * 8 + 1];      \
    bq2 = gBp[(t) * 8 + 2];      \
    bq3 = gBp[(t) * 8 + 3];      \
  } while (0)

#define DMA_A(t, Ad)                                   \
  do {                                                 \
    gld_lds16(gA0 + (t) * GBK, (Ad) + loA);            \
    gld_lds16(gA1 + (t) * GBK, (Ad) + loA + 16 * GBK); \
  } while (0)

#define WRITEB(Bb)                                                          \
  do {                                                                     \
    sq = fmaf(bq0.x, bq0.x, sq); sq = fmaf(bq0.y, bq0.y, sq);              \
    sq = fmaf(bq0.z, bq0.z, sq); sq = fmaf(bq0.w, bq0.w, sq);              \
    sq = fmaf(bq1.x, bq1.x, sq); sq = fmaf(bq1.y, bq1.y, sq);              \
    sq = fmaf(bq1.z, bq1.z, sq); sq = fmaf(bq1.w, bq1.w, sq);              \
    sq = fmaf(bq2.x, bq2.x, sq); sq = fmaf(bq2.y, bq2.y, sq);              \
    sq = fmaf(bq2.z, bq2.z, sq); sq = fmaf(bq2.w, bq2.w, sq);              \
    sq = fmaf(bq3.x, bq3.x, sq); sq = fmaf(bq3.y, bq3.y, sq);              \
    sq = fmaf(bq3.z, bq3.z, sq); sq = fmaf(bq3.w, bq3.w, sq);              \
    uint4 w0, w1;                                                          \
    w0.x = cvt2(bq0.x, bq0.y); w0.y = cvt2(bq0.z, bq0.w);                  \
    w0.z = cvt2(bq1.x, bq1.y); w0.w = cvt2(bq1.z, bq1.w);                  \
    w1.x = cvt2(bq2.x, bq2.y); w1.y = cvt2(bq2.z, bq2.w);                  \
    w1.z = cvt2(bq3.x, bq3.y); w1.w = cvt2(bq3.z, bq3.w);                  \
    *reinterpret_cast<uint4*>((char*)(Bb) + wb0) = w0;                     \
    *reinterpret_cast<uint4*>((char*)(Bb) + wb1) = w1;                     \
  } while (0)

#define COMPUTE(Ab, Bb)                                                        \
  do {                                                                         \
    bf16x8 af[4], bfr[4];                                                      \
    _Pragma("unroll") for (int i = 0; i < 4; ++i) {                            \
      af[i] = *reinterpret_cast<const bf16x8*>((const char*)(Ab) + aoff[i]);   \
      bfr[i] = *reinterpret_cast<const bf16x8*>((const char*)(Bb) + boff[i]);  \
    }                                                                          \
    _Pragma("unroll") for (int i = 0; i < 4; ++i)                              \
        _Pragma("unroll") for (int j = 0; j < 4; ++j) acc[i][j] =              \
            __builtin_amdgcn_mfma_f32_16x16x32_bf16(af[i], bfr[j], acc[i][j],  \
                                                    0, 0, 0);                  \
  } while (0)

#define VMW0 asm volatile("s_waitcnt vmcnt(0)" ::: "memory")
#define LGKM0 asm volatile("s_waitcnt lgkmcnt(0)" ::: "memory")
#define BARR __builtin_amdgcn_s_barrier()
#define SB0 __builtin_amdgcn_sched_barrier(0)

  // prologue
  LOADB(0); DMA_A(0, A0);
  VMW0; SB0;
  WRITEB(B0);
  LOADB(1); DMA_A(1, A1);
  LGKM0; BARR; SB0;

#pragma unroll
  for (int t = 0; t < NKT; ++t) {
    const ushort* Ab = (t & 1) ? A1 : A0;
    const ushort* Bb = (t & 1) ? B1 : B0;
    COMPUTE(Ab, Bb);
    if (t < NKT - 1) {
      VMW0; BARR; SB0;          // regs(t+1)+DMA(t+1) landed; all waves done reading [t&1]
      ushort* Bw = (t & 1) ? B0 : B1;   // (t+1)&1
      WRITEB(Bw);
      if (t < NKT - 2) {
        LOADB(t + 2);
        ushort* Ad = (t & 1) ? A1 : A0;  // (t+2)&1 == t&1, read of it just ended
        DMA_A(t + 2, Ad);
      }
      LGKM0; BARR; SB0;         // own ds_writes visible; DMA/loads stay in flight
    }
  }

  // ---- invM from reg-accumulated sumsq (each element counted once) ----
  __syncthreads();  // loop fully done; also drains outstanding counters
  {
    float s2 = sq + __shfl_xor(sq, 1);  // pair (2r, 2r+1) -> full row r
    if (hB == 0) {
      double inv = 1.0 / fmax(sqrt((double)s2), 1e-12);
      invml[rB] = (float)inv;
      if (bm0 == 0) invMg[(size_t)k * NMEM + bn0 + rB] = inv;
    }
  }
  __syncthreads();

  // ---------- epilogue ----------
  size_t kb = (size_t)k * BATCH;
  float fi[4][4];
#pragma unroll
  for (int i = 0; i < 4; ++i)
#pragma unroll
    for (int r = 0; r < 4; ++r)
      fi[i][r] = (float)invF[kb + bm0 + wr + i * 16 + rgrp + r];
  float im[4];
#pragma unroll
  for (int j = 0; j < 4; ++j) im[j] = invml[wc + j * 16 + l15];

  // soft zero-block (coalesced float4); top-5 scatter happens in merge
  {
    const f32x4 z = (f32x4){0.f, 0.f, 0.f, 0.f};
#pragma unroll
    for (int p = 0; p < 16; ++p) {
      int u = p * 256 + tid;
      int row = u >> 5, unit = u & 31;
      *reinterpret_cast<f32x4*>(soft + (kb + bm0 + row) * NMEM + bn0 + unit * 4) = z;
    }
  }

  // 4 quarters of 32 rows: acc -> LDS chunk -> coalesced sim store + top-4 scan
  // qt loop fully unrolled (rule #20: runtime-indexed acc -> scratch disaster)
  float* chunk = (float*)smem;                  // 16896 B
  float2* lists = (float2*)(smem + 24576);      // 8192 B
#pragma unroll
  for (int qt = 0; qt < 4; ++qt) {
    __syncthreads();
    if (wr == (qt >> 1) * 64) {
      const int ibase = (qt & 1) * 2;
#pragma unroll
      for (int ii = 0; ii < 2; ++ii) {
        const int i = ibase + ii;
        int rc0 = ii * 16 + rgrp;
#pragma unroll
        for (int j = 0; j < 4; ++j)
#pragma unroll
          for (int r = 0; r < 4; ++r)
            chunk[(rc0 + r) * CHS + wc + j * 16 + l15] =
                acc[i][j][r] * fi[i][r] * im[j];
      }
    }
    __syncthreads();
    int grow = bm0 + qt * 32;
#pragma unroll
    for (int uu = 0; uu < 4; ++uu) {
      int u = uu * 256 + tid;
      int rc = u >> 5, cu = u & 31;
      f32x4 v = *reinterpret_cast<const f32x4*>(chunk + rc * CHS + cu * 4);
      *reinterpret_cast<f32x4*>(sim + (kb + grow + rc) * NMEM + bn0 + cu * 4) = v;
    }
    int rc = tid >> 3, q8 = tid & 7;
    float v4[4] = {-INFINITY, -INFINITY, -INFINITY, -INFINITY};
    int i4[4] = {0, 0, 0, 0};
#pragma unroll
    for (int j = 0; j < 16; ++j) {
      int cc = q8 + 8 * j;
      float v = chunk[rc * CHS + cc];
      if (v > v4[3]) {
        v4[3] = v; i4[3] = cc;
        if (v4[3] > v4[2]) { float t = v4[3]; v4[3] = v4[2]; v4[2] = t; int s = i4[3]; i4[3] = i4[2]; i4[2] = s; }
        if (v4[2] > v4[1]) { float t = v4[2]; v4[2] = v4[1]; v4[1] = t; int s = i4[2]; i4[2] = i4[1]; i4[1] = s; }
        if (v4[1] > v4[0]) { float t = v4[1]; v4[1] = v4[0]; v4[0] = t; int s = i4[1]; i4[1] = i4[0]; i4[0] = s; }
      }
    }
#pragma unroll
    for (int s = 0; s < 4; ++s)
      lists[(rc * 8 + q8) * 4 + s] = make_float2(v4[s], __builtin_bit_cast(float, i4[s]));
    __syncthreads();
    if (q8 == 0) {
      float mv[4] = {-INFINITY, -INFINITY, -INFINITY, -INFINITY};
      int mi[4] = {0, 0, 0, 0};
#pragma unroll
      for (int e = 0; e < 32; ++e) {
        float2 pe = lists[rc * 32 + e];
        float v = pe.x; int ix = __builtin_bit_cast(int, pe.y);
        if (v > mv[3]) {
          mv[3] = v; mi[3] = ix;
          if (mv[3] > mv[2]) { float t = mv[3]; mv[3] = mv[2]; mv[2] = t; int s = mi[3]; mi[3] = mi[2]; mi[2] = s; }
          if (mv[2] > mv[1]) { float t = mv[2]; mv[2] = mv[1]; mv[1] = t; int s = mi[2]; mi[2] = mi[1]; mi[1] = s; }
          if (mv[1] > mv[0]) { float t = mv[1]; mv[1] = mv[0]; mv[0] = t; int s = mi[1]; mi[1] = mi[0]; mi[0] = s; }
        }
      }
      float2* Prow = P + ((size_t)(kb + grow + rc) * NXBLK + ntile) * 4;
#pragma unroll
      for (int s = 0; s < 4; ++s)
        Prow[s] = make_float2(mv[s], __builtin_bit_cast(float, mi[s] + bn0));
    }
  }
#undef LOADB
#undef DMA_A
#undef WRITEB
#undef COMPUTE
#undef VMW0
#undef LGKM0
#undef BARR
#undef SB0
}

// ---------------- merge partials + fp64 refine + softmax + entropy ----------

__global__ __launch_bounds__(256) void merge_kernel(
    const float* __restrict__ F, const float* __restrict__ M,
    const double* __restrict__ invF, const double* __restrict__ invM,
    const float2* __restrict__ P, float* __restrict__ soft,
    float* __restrict__ ent) {
  int kb = blockIdx.x;  // 0..1535
  int k = kb / BATCH;
  int tid = threadIdx.x;
  float* orow = soft + (size_t)kb * NMEM;

  __shared__ float sval[1024];
  __shared__ int   sidx[1024];
  const float2* Prow = P + (size_t)kb * NXBLK * 4;
#pragma unroll
  for (int j = 0; j < 4; ++j) {
    float2 e = Prow[tid * 4 + j];
    sval[tid * 4 + j] = e.x;
    sidx[tid * 4 + j] = __builtin_bit_cast(int, e.y);
  }
  __syncthreads();

  __shared__ float rv[256]; __shared__ int rp[256];
  __shared__ float cand_v[8]; __shared__ int cand_i[8];
  for (int r = 0; r < 8; ++r) {
    float best = -INFINITY; int bpos = tid * 4;
#pragma unroll
    for (int j = 0; j < 4; ++j) {
      float v = sval[tid * 4 + j];
      if (v > best) { best = v; bpos = tid * 4 + j; }
    }
    rv[tid] = best; rp[tid] = bpos;
    __syncthreads();
    for (int st = 128; st > 0; st >>= 1) {
      if (tid < st && rv[tid + st] > rv[tid]) { rv[tid] = rv[tid + st]; rp[tid] = rp[tid + st]; }
      __syncthreads();
    }
    if (tid == 0) {
      cand_v[r] = rv[0]; cand_i[r] = sidx[rp[0]];
      sval[rp[0]] = -INFINITY;
    }
    __syncthreads();
  }

  // fp64 refinement of the 8 candidates (exact re-ranking at the 5/6 boundary)
  __shared__ double dred[256];
  __shared__ double cval[8];
  const float* fr = F + (size_t)kb * DIM;
  double invf = invF[kb];
  for (int c = 0; c < 8; ++c) {
    const float* mr = M + ((size_t)k * NMEM + cand_i[c]) * DIM;
    double s = 0.0;
    for (int d = tid; d < DIM; d += 256) s += (double)fr[d] * (double)mr[d];
    dred[tid] = s; __syncthreads();
    for (int st = 128; st > 0; st >>= 1) {
      if (tid < st) dred[tid] += dred[tid + st];
      __syncthreads();
    }
    if (tid == 0) cval[c] = dred[0] * invf * invM[(size_t)k * NMEM + cand_i[c]];
    __syncthreads();
  }

  if (tid == 0) {
    int ord[8];
    for (int i = 0; i < 8; ++i) ord[i] = i;
    for (int i = 0; i < 5; ++i) {
      int best = i;
      for (int j = i + 1; j < 8; ++j) {
        float fa = (float)cval[ord[j]], fb = (float)cval[ord[best]];
        bool better = (fa != fb) ? (fa > fb) : (cand_i[ord[j]] < cand_i[ord[best]]);
        if (better) best = j;
      }
      int t = ord[i]; ord[i] = ord[best]; ord[best] = t;
    }
    float v5[5]; int i5[5];
    float vmax = -INFINITY;
    for (int i = 0; i < 5; ++i) {
      v5[i] = cand_v[ord[i]]; i5[i] = cand_i[ord[i]];
      vmax = fmaxf(vmax, v5[i]);
    }
    float e[5], Z = 0.f;
    float xm = vmax / 3.0f;
    for (int i = 0; i < 5; ++i) { e[i] = expf(v5[i] / 3.0f - xm); Z += e[i]; }
    float ent_s = 0.f;
    for (int i = 0; i < 5; ++i) {
      float p = e[i] / Z;
      orow[i5[i]] = p;
      ent_s += p * logf(p);
    }
    float tiny = 1e-8f * logf(1e-8f);
    ent[kb] = -(ent_s + (float)(NMEM - 5) * tiny);
  }
}

// ---------------- entropy weights ----------------

__global__ __launch_bounds__(256) void w_kernel(const float* __restrict__ ent,
                                                float* __restrict__ wout) {
  int k = blockIdx.x; int tid = threadIdx.x;
  float e = ent[k * BATCH + tid];
  float wv = expf(-e);
  __shared__ float red[256];
  red[tid] = wv; __syncthreads();
  for (int st = 128; st > 0; st >>= 1) {
    if (tid < st) red[tid] += red[tid + st];
    __syncthreads();
  }
  float mean = red[0] / (float)BATCH;
  wout[k * BATCH + tid] = wv / (mean + 1e-8f);
}

// ---------------- launch ----------------

extern "C" void kernel_launch(void* const* d_in, const int* in_sizes, int n_in,
                              void* d_out, int out_size, void* d_ws, size_t ws_size,
                              hipStream_t stream) {
  (void)in_sizes; (void)n_in; (void)out_size; (void)ws_size;
  const float* F = (const float*)d_in[0];   // [KP, BATCH, DIM] fp32
  const float* M = (const float*)d_in[1];   // [KP, NMEM, DIM] fp32
  float* out = (float*)d_out;
  size_t simsz = (size_t)KP * BATCH * NMEM;
  float* soft = out;
  float* sim = out + simsz;
  float* wout = out + 2 * simsz;

  // workspace: Fb bf16 (2.4 MB) + invM f64 + invF f64 + ent + P (~16 MB)
  ushort* Fb = (ushort*)d_ws;                               // KP*BATCH*DIM bf16
  double* invM = (double*)(Fb + (size_t)KP * BATCH * DIM);  // KP*NMEM f64
  double* invF = invM + (size_t)KP * NMEM;                  // KP*BATCH f64
  float* ent = (float*)(invF + KP * BATCH);                 // KP*BATCH f32
  float2* P = (float2*)(ent + NROWS);                       // NROWS*NXBLK*4 float2

  prep_kernel<<<KP * BATCH / 4, 256, 0, stream>>>(F, Fb, invF, KP * BATCH);
  gemm_kernel<<<(BATCH / GBM) * (NMEM / GBN) * KP, 256, 0, stream>>>(M, Fb, invF, invM, sim, soft, P);
  merge_kernel<<<NROWS, 256, 0, stream>>>(F, M, invF, invM, P, soft, ent);
  w_kernel<<<KP, 256, 0, stream>>>(ent, wout);
}